// Round 1
// baseline (162.415 us; speedup 1.0000x reference)
//
#include <hip/hip_runtime.h>
#include <hip/hip_cooperative_groups.h>
#include <math.h>

namespace cg = cooperative_groups;

#define T_END_F 100.0f
#define N_TAB 4096
#define HID 128
#define EVB 8             // table entries per block
#define EVW 2             // table entries per wave (4 waves/block)
#define NBLK_TAB (N_TAB / EVB)   // 512 blocks
#define N_MC_TOTAL 92160  // 15 * 16 * 384
#define TF_HALF 46080u
#define FUSED_BLOCKS 512
#define NSLOT 16

// ---------- math helpers ----------
__device__ __forceinline__ float softplusf(float z){
  return fmaxf(z, 0.0f) + log1pf(expf(-fabsf(z)));
}

__device__ __forceinline__ unsigned rotl32(unsigned x, unsigned d){
  return (x << d) | (x >> (32u - d));
}

// Bit-exact JAX threefry2x32 uniform for key(42), total count 92160.
__device__ float threefry_u01(unsigned idx){
  unsigned i0, i1;
  bool second = idx >= TF_HALF;
  if (second){ i0 = idx - TF_HALF; i1 = idx; }
  else       { i0 = idx;           i1 = idx + TF_HALF; }
  const unsigned ks0 = 0u;
  const unsigned ks1 = 42u;
  const unsigned ks2 = 0x1BD11BDAu ^ ks0 ^ ks1;
  unsigned x0 = i0 + ks0;
  unsigned x1 = i1 + ks1;
#define TF_R(r) { x0 += x1; x1 = rotl32(x1, (r)); x1 ^= x0; }
  TF_R(13) TF_R(15) TF_R(26) TF_R(6)
  x0 += ks1; x1 += ks2 + 1u;
  TF_R(17) TF_R(29) TF_R(16) TF_R(24)
  x0 += ks2; x1 += ks0 + 2u;
  TF_R(13) TF_R(15) TF_R(26) TF_R(6)
  x0 += ks0; x1 += ks1 + 3u;
  TF_R(17) TF_R(29) TF_R(16) TF_R(24)
  x0 += ks1; x1 += ks2 + 4u;
  TF_R(13) TF_R(15) TF_R(26) TF_R(6)
  x0 += ks2; x1 += ks0 + 5u;
#undef TF_R
  unsigned bits = second ? x1 : x0;
  unsigned fb = (bits >> 9) | 0x3F800000u;
  return __uint_as_float(fb) - 1.0f;
}

// linear interp lookup from a generic (global) pointer, x in [0, T_END]
__device__ __forceinline__ float table_f(const float* __restrict__ tab, float x){
  float pos = x * ((float)(N_TAB - 1) / T_END_F);
  int i = (int)pos;
  if (i < 0) i = 0;
  if (i > N_TAB - 2) i = N_TAB - 2;
  float fr = pos - (float)i;
  float a = tab[i];
  float b = tab[i + 1];
  return fmaf(fr, b - a, a);
}

// LDS-resident table lookup (macro so the addrspace(3) access stays visible)
#define TABLE_LDS(xval) ({                                        \
  float _pos = (xval) * ((float)(N_TAB - 1) / T_END_F);           \
  int _i = (int)_pos;                                             \
  if (_i < 0) _i = 0;                                             \
  if (_i > N_TAB - 2) _i = N_TAB - 2;                             \
  float _fr = _pos - (float)_i;                                   \
  float _a = sm_tab[_i];                                          \
  float _b = sm_tab[_i + 1];                                      \
  fmaf(_fr, _b - _a, _a); })

// ---------- table build ----------
// 256 threads = 4 waves. Each wave owns EVW=2 table entries (private LDS rows,
// no cross-wave deps -> no __syncthreads). All 4 waves stream the same weight
// addresses -> L1 reuse. Thread owns hidden units k0=lane, k1=lane+64.
__device__ __forceinline__ void dense_tanh_layer(
    const float (*__restrict__ hin)[HID], float (*__restrict__ hout)[HID],
    const float* __restrict__ W, const float* __restrict__ bv,
    int k0, int k1, int ebase)
{
  float acc0[EVW], acc1[EVW];
  {
    float ba = bv[k0], bb = bv[k1];
#pragma unroll
    for (int e = 0; e < EVW; ++e){ acc0[e] = ba; acc1[e] = bb; }
  }
#pragma unroll 4
  for (int j = 0; j < HID; j += 4){
    float wa0 = W[(j+0)*HID + k0];
    float wa1 = W[(j+1)*HID + k0];
    float wa2 = W[(j+2)*HID + k0];
    float wa3 = W[(j+3)*HID + k0];
    float wb0 = W[(j+0)*HID + k1];
    float wb1 = W[(j+1)*HID + k1];
    float wb2 = W[(j+2)*HID + k1];
    float wb3 = W[(j+3)*HID + k1];
#pragma unroll
    for (int e = 0; e < EVW; ++e){
      float4 h = *(const float4*)&hin[ebase + e][j];   // wave-uniform LDS broadcast
      float a0 = acc0[e], a1 = acc1[e];
      a0 = fmaf(h.x, wa0, a0); a1 = fmaf(h.x, wb0, a1);
      a0 = fmaf(h.y, wa1, a0); a1 = fmaf(h.y, wb1, a1);
      a0 = fmaf(h.z, wa2, a0); a1 = fmaf(h.z, wb2, a1);
      a0 = fmaf(h.w, wa3, a0); a1 = fmaf(h.w, wb3, a1);
      acc0[e] = a0; acc1[e] = a1;
    }
  }
#pragma unroll
  for (int e = 0; e < EVW; ++e){
    hout[ebase + e][k0] = tanhf(acc0[e]);
    hout[ebase + e][k1] = tanhf(acc1[e]);
  }
}

// ---------- merged cooperative kernel ----------
// Phase 1: 512 blocks x 4 waves build 8 table entries each (identical math to
//          the old build_table_kernel -> bit-identical table).
// grid.sync()
// Phase 2: stage the 16 KB table into LDS, then pairs log-sum + MC integral,
//          16-slot atomics + ticket finalize (identical to old fused_kernel).
__global__ __launch_bounds__(256) void mc_nll_fused(
    const float* __restrict__ W1, const float* __restrict__ b1v,
    const float* __restrict__ W2, const float* __restrict__ b2v,
    const float* __restrict__ W3, const float* __restrict__ b3v,
    const float* __restrict__ W4, const float* __restrict__ b4v,
    const float* __restrict__ t,        // [16][384]
    const int* __restrict__ seq_lens,   // [16]
    const float* __restrict__ bg,
    float* __restrict__ tab,
    float* __restrict__ slots,          // [2*NSLOT]: logs then mc
    int* __restrict__ cnt,
    float* __restrict__ out)
{
  __shared__ float hA[EVB][HID];     // 4 KB
  __shared__ float hB[EVB][HID];     // 4 KB
  __shared__ float sm_tab[N_TAB];    // 16 KB
  __shared__ float redL[4], redM[4];

  const int tid  = threadIdx.x;
  const int wv   = tid >> 6;
  const int lane = tid & 63;
  const int k0 = lane, k1 = lane + 64;
  const int ebase = wv * EVW;
  const int base = blockIdx.x * EVB;
  const float dt = T_END_F / (float)(N_TAB - 1);

  // zero accumulators (visible to all after grid.sync)
  if (blockIdx.x == 0 && tid < 2 * NSLOT + 1){
    if (tid < 2 * NSLOT) slots[tid] = 0.0f;
    else *cnt = 0;
  }

  // ---- phase 1: table build ----
  // layer 1: scalar -> 128
  {
    float wa = W1[k0], wb = W1[k1];
    float ba = b1v[k0], bb = b1v[k1];
#pragma unroll
    for (int e = 0; e < EVW; ++e){
      float x = (float)(base + ebase + e) * dt;
      hA[ebase + e][k0] = tanhf(fmaf(x, wa, ba));
      hA[ebase + e][k1] = tanhf(fmaf(x, wb, bb));
    }
  }
  dense_tanh_layer(hA, hB, W2, b2v, k0, k1, ebase);   // layer 2
  dense_tanh_layer(hB, hA, W3, b3v, k0, k1, ebase);   // layer 3
  // layer 4: 128 -> 1, softplus
  {
    float wa = W4[k0], wb = W4[k1];
    float b4s = b4v[0];
#pragma unroll
    for (int e = 0; e < EVW; ++e){
      float p = hA[ebase + e][k0] * wa + hA[ebase + e][k1] * wb;
      p += __shfl_xor(p, 32);
      p += __shfl_xor(p, 16);
      p += __shfl_xor(p, 8);
      p += __shfl_xor(p, 4);
      p += __shfl_xor(p, 2);
      p += __shfl_xor(p, 1);
      if (lane == 0) tab[base + ebase + e] = softplusf(p + b4s);
    }
  }

  cg::this_grid().sync();

  // ---- phase 2: stage table to LDS ----
  {
    const float4* g4 = (const float4*)tab;
    float4* s4 = (float4*)sm_tab;
#pragma unroll
    for (int q = 0; q < (N_TAB / 4) / 256; ++q)   // 4 iterations
      s4[q * 256 + tid] = g4[q * 256 + tid];
  }
  __syncthreads();

  const float bgv = bg[0];
  const int gwave = blockIdx.x * 4 + wv;   // 0..2047

  float logsum = 0.0f;   // only lane 0 accumulates
  float mcv    = 0.0f;

  // pairs: tasks gwave, gwave+2048, gwave+4096
#pragma unroll
  for (int k = 0; k < 3; ++k){
    unsigned task = (unsigned)gwave + (unsigned)k * 2048u;  // < 6144
    unsigned b = task / 384u;
    int i = (int)(task - b * 384u);
    if (i < seq_lens[b]){
      const float* tb = t + b * 384u;
      float ti = tb[i];
      float s = 0.0f;
      for (int j = lane; j < i; j += 64)
        s += TABLE_LDS(ti - tb[j]);
      s += __shfl_xor(s, 32);
      s += __shfl_xor(s, 16);
      s += __shfl_xor(s, 8);
      s += __shfl_xor(s, 4);
      s += __shfl_xor(s, 2);
      s += __shfl_xor(s, 1);
      if (lane == 0) logsum += logf(s + bgv);
    }
  }

  // Monte Carlo sample
  {
    int idx = blockIdx.x * 256 + tid;
    if (idx < N_MC_TOTAL){
      int l = idx % 384;
      int b = (idx / 384) & 15;
      if (l < seq_lens[b]){
        float tv = t[b * 384 + l];
        float dl = T_END_F - tv;
        float u  = threefry_u01((unsigned)idx);
        mcv = (TABLE_LDS(u * dl) + 1e-10f) * dl;
      }
    }
  }
  mcv += __shfl_xor(mcv, 32);
  mcv += __shfl_xor(mcv, 16);
  mcv += __shfl_xor(mcv, 8);
  mcv += __shfl_xor(mcv, 4);
  mcv += __shfl_xor(mcv, 2);
  mcv += __shfl_xor(mcv, 1);

  if (lane == 0){ redL[wv] = logsum; redM[wv] = mcv; }
  __syncthreads();
  if (tid == 0){
    float bl = redL[0] + redL[1] + redL[2] + redL[3];
    float bm = redM[0] + redM[1] + redM[2] + redM[3];
    int slot = blockIdx.x & (NSLOT - 1);
    atomicAdd(&slots[slot], bl);
    atomicAdd(&slots[NSLOT + slot], bm);
    __threadfence();
    int old = atomicAdd(cnt, 1);
    if (old == (int)gridDim.x - 1){
      float sl = 0.0f, sm = 0.0f;
      for (int q = 0; q < NSLOT; ++q){
        sl += atomicAdd(&slots[q], 0.0f);
        sm += atomicAdd(&slots[NSLOT + q], 0.0f);
      }
      float lamb_ints_total = sm * (1.0f / 15.0f) + 16.0f * T_END_F * bgv;
      out[0] = -(sl - lamb_ints_total) / 16.0f;
    }
  }
}

// ---------- fallback path (two kernels, identical to previous version) ----------
__global__ __launch_bounds__(256) void build_table_kernel(
    const float* __restrict__ W1, const float* __restrict__ b1v,
    const float* __restrict__ W2, const float* __restrict__ b2v,
    const float* __restrict__ W3, const float* __restrict__ b3v,
    const float* __restrict__ W4, const float* __restrict__ b4v,
    float* __restrict__ tab, float* __restrict__ slots, int* __restrict__ cnt)
{
  __shared__ float hA[EVB][HID];
  __shared__ float hB[EVB][HID];
  const int tid  = threadIdx.x;
  const int wv   = tid >> 6;
  const int lane = tid & 63;
  const int k0 = lane, k1 = lane + 64;
  const int ebase = wv * EVW;
  const int base = blockIdx.x * EVB;
  const float dt = T_END_F / (float)(N_TAB - 1);

  if (blockIdx.x == 0 && tid < 2 * NSLOT + 1){
    if (tid < 2 * NSLOT) slots[tid] = 0.0f;
    else *cnt = 0;
  }

  {
    float wa = W1[k0], wb = W1[k1];
    float ba = b1v[k0], bb = b1v[k1];
#pragma unroll
    for (int e = 0; e < EVW; ++e){
      float x = (float)(base + ebase + e) * dt;
      hA[ebase + e][k0] = tanhf(fmaf(x, wa, ba));
      hA[ebase + e][k1] = tanhf(fmaf(x, wb, bb));
    }
  }
  dense_tanh_layer(hA, hB, W2, b2v, k0, k1, ebase);
  dense_tanh_layer(hB, hA, W3, b3v, k0, k1, ebase);
  {
    float wa = W4[k0], wb = W4[k1];
    float b4s = b4v[0];
#pragma unroll
    for (int e = 0; e < EVW; ++e){
      float p = hA[ebase + e][k0] * wa + hA[ebase + e][k1] * wb;
      p += __shfl_xor(p, 32);
      p += __shfl_xor(p, 16);
      p += __shfl_xor(p, 8);
      p += __shfl_xor(p, 4);
      p += __shfl_xor(p, 2);
      p += __shfl_xor(p, 1);
      if (lane == 0) tab[base + ebase + e] = softplusf(p + b4s);
    }
  }
}

__global__ __launch_bounds__(256) void fused_kernel(
    const float* __restrict__ t,
    const int* __restrict__ seq_lens,
    const float* __restrict__ bg,
    const float* __restrict__ tab,
    float* __restrict__ slots,
    int* __restrict__ cnt,
    float* __restrict__ out)
{
  const int tid  = threadIdx.x;
  const int lane = tid & 63;
  const int wv   = tid >> 6;
  const int gwave = blockIdx.x * 4 + wv;
  const float bgv = bg[0];

  float logsum = 0.0f;
  float mcv    = 0.0f;

#pragma unroll
  for (int k = 0; k < 3; ++k){
    unsigned task = (unsigned)gwave + (unsigned)k * 2048u;
    unsigned b = task / 384u;
    int i = (int)(task - b * 384u);
    if (i < seq_lens[b]){
      const float* tb = t + b * 384u;
      float ti = tb[i];
      float s = 0.0f;
      for (int j = lane; j < i; j += 64)
        s += table_f(tab, ti - tb[j]);
      s += __shfl_xor(s, 32);
      s += __shfl_xor(s, 16);
      s += __shfl_xor(s, 8);
      s += __shfl_xor(s, 4);
      s += __shfl_xor(s, 2);
      s += __shfl_xor(s, 1);
      if (lane == 0) logsum += logf(s + bgv);
    }
  }

  {
    int idx = blockIdx.x * 256 + tid;
    if (idx < N_MC_TOTAL){
      int l = idx % 384;
      int b = (idx / 384) & 15;
      if (l < seq_lens[b]){
        float tv = t[b * 384 + l];
        float dl = T_END_F - tv;
        float u  = threefry_u01((unsigned)idx);
        mcv = (table_f(tab, u * dl) + 1e-10f) * dl;
      }
    }
  }
  mcv += __shfl_xor(mcv, 32);
  mcv += __shfl_xor(mcv, 16);
  mcv += __shfl_xor(mcv, 8);
  mcv += __shfl_xor(mcv, 4);
  mcv += __shfl_xor(mcv, 2);
  mcv += __shfl_xor(mcv, 1);

  __shared__ float redL[4], redM[4];
  if (lane == 0){ redL[wv] = logsum; redM[wv] = mcv; }
  __syncthreads();
  if (tid == 0){
    float bl = redL[0] + redL[1] + redL[2] + redL[3];
    float bm = redM[0] + redM[1] + redM[2] + redM[3];
    int slot = blockIdx.x & (NSLOT - 1);
    atomicAdd(&slots[slot], bl);
    atomicAdd(&slots[NSLOT + slot], bm);
    __threadfence();
    int old = atomicAdd(cnt, 1);
    if (old == (int)gridDim.x - 1){
      float sl = 0.0f, sm = 0.0f;
      for (int q = 0; q < NSLOT; ++q){
        sl += atomicAdd(&slots[q], 0.0f);
        sm += atomicAdd(&slots[NSLOT + q], 0.0f);
      }
      float lamb_ints_total = sm * (1.0f / 15.0f) + 16.0f * T_END_F * bgv;
      out[0] = -(sl - lamb_ints_total) / 16.0f;
    }
  }
}

extern "C" void kernel_launch(void* const* d_in, const int* in_sizes, int n_in,
                              void* d_out, int out_size, void* d_ws, size_t ws_size,
                              hipStream_t stream)
{
  const float* seq_pads = (const float*)d_in[0];
  const int*   seq_lens = (const int*)d_in[1];
  const float* bg       = (const float*)d_in[2];
  const float* W1 = (const float*)d_in[3];
  const float* b1 = (const float*)d_in[4];
  const float* W2 = (const float*)d_in[5];
  const float* b2 = (const float*)d_in[6];
  const float* W3 = (const float*)d_in[7];
  const float* b3 = (const float*)d_in[8];
  const float* W4 = (const float*)d_in[9];
  const float* b4 = (const float*)d_in[10];
  float* out = (float*)d_out;

  float* tab   = (float*)d_ws;          // N_TAB floats
  float* slots = tab + N_TAB;           // 2*NSLOT floats
  int*   cnt   = (int*)(slots + 2 * NSLOT);

  void* args[] = {
    (void*)&W1, (void*)&b1, (void*)&W2, (void*)&b2,
    (void*)&W3, (void*)&b3, (void*)&W4, (void*)&b4,
    (void*)&seq_pads, (void*)&seq_lens, (void*)&bg,
    (void*)&tab, (void*)&slots, (void*)&cnt, (void*)&out
  };
  hipError_t err = hipLaunchCooperativeKernel(
      reinterpret_cast<void*>(mc_nll_fused), dim3(FUSED_BLOCKS), dim3(256),
      args, 0, stream);
  if (err != hipSuccess){
    // fallback: original two-kernel path (stream-ordered)
    build_table_kernel<<<NBLK_TAB, 256, 0, stream>>>(W1, b1, W2, b2, W3, b3, W4, b4,
                                                     tab, slots, cnt);
    fused_kernel<<<FUSED_BLOCKS, 256, 0, stream>>>(seq_pads, seq_lens, bg, tab,
                                                   slots, cnt, out);
  }
}

// Round 2
// 136.521 us; speedup vs baseline: 1.1897x; 1.1897x over previous
//
#include <hip/hip_runtime.h>
#include <math.h>

#define T_END_F 100.0f
#define N_TAB 4096
#define HID 128
#define N_MC_TOTAL 92160  // 15 * 16 * 384
#define TF_HALF 46080u
#define NSLOT 16

// build kernel geometry: thread = (entry, unit). 4 entries/block x 128 units
// = 512 threads; 1024 blocks -> 8192 waves = 32 waves/CU (4x the old occupancy).
#define B_EV 4
#define B_THREADS 512
#define NBLK_BUILD (N_TAB / B_EV)   // 1024

// fused kernel geometry: 1536 blocks x 4 waves = 6144 waves = 24 waves/CU;
// exactly one (b,i) pair-task per wave; MC thread-per-sample in blocks 0..359.
#define FUSED_BLOCKS 1536

// ---------- math helpers ----------
__device__ __forceinline__ float softplusf(float z){
  return fmaxf(z, 0.0f) + log1pf(expf(-fabsf(z)));
}

__device__ __forceinline__ unsigned rotl32(unsigned x, unsigned d){
  return (x << d) | (x >> (32u - d));
}

// Bit-exact JAX threefry2x32 uniform for key(42), total count 92160.
__device__ float threefry_u01(unsigned idx){
  unsigned i0, i1;
  bool second = idx >= TF_HALF;
  if (second){ i0 = idx - TF_HALF; i1 = idx; }
  else       { i0 = idx;           i1 = idx + TF_HALF; }
  const unsigned ks0 = 0u;
  const unsigned ks1 = 42u;
  const unsigned ks2 = 0x1BD11BDAu ^ ks0 ^ ks1;
  unsigned x0 = i0 + ks0;
  unsigned x1 = i1 + ks1;
#define TF_R(r) { x0 += x1; x1 = rotl32(x1, (r)); x1 ^= x0; }
  TF_R(13) TF_R(15) TF_R(26) TF_R(6)
  x0 += ks1; x1 += ks2 + 1u;
  TF_R(17) TF_R(29) TF_R(16) TF_R(24)
  x0 += ks2; x1 += ks0 + 2u;
  TF_R(13) TF_R(15) TF_R(26) TF_R(6)
  x0 += ks0; x1 += ks1 + 3u;
  TF_R(17) TF_R(29) TF_R(16) TF_R(24)
  x0 += ks1; x1 += ks2 + 4u;
  TF_R(13) TF_R(15) TF_R(26) TF_R(6)
  x0 += ks2; x1 += ks0 + 5u;
#undef TF_R
  unsigned bits = second ? x1 : x0;
  unsigned fb = (bits >> 9) | 0x3F800000u;
  return __uint_as_float(fb) - 1.0f;
}

// LDS-resident table lookup
#define TABLE_LDS(xval) ({                                        \
  float _pos = (xval) * ((float)(N_TAB - 1) / T_END_F);           \
  int _i = (int)_pos;                                             \
  if (_i < 0) _i = 0;                                             \
  if (_i > N_TAB - 2) _i = N_TAB - 2;                             \
  float _fr = _pos - (float)_i;                                   \
  float _a = sm_tab[_i];                                          \
  float _b = sm_tab[_i + 1];                                      \
  fmaf(_fr, _b - _a, _a); })

// dense dot for one (entry, unit): same ascending-j single-acc fmaf order as
// the original dense_tanh_layer -> bit-identical results per (entry, unit).
__device__ __forceinline__ float dense_dot(
    const float* __restrict__ hrow,   // LDS row [HID], wave-uniform reads
    const float* __restrict__ W,      // [HID][HID] row-major
    int k, float bias)
{
  float acc = bias;
#pragma unroll 4
  for (int j = 0; j < HID; j += 4){
    float4 h = *(const float4*)&hrow[j];   // wave-uniform LDS broadcast
    acc = fmaf(h.x, W[(j+0)*HID + k], acc);
    acc = fmaf(h.y, W[(j+1)*HID + k], acc);
    acc = fmaf(h.z, W[(j+2)*HID + k], acc);
    acc = fmaf(h.w, W[(j+3)*HID + k], acc);
  }
  return acc;
}

// ---------- table build: 1024 blocks x 512 threads ----------
__global__ __launch_bounds__(B_THREADS) void build_table_kernel(
    const float* __restrict__ W1, const float* __restrict__ b1v,
    const float* __restrict__ W2, const float* __restrict__ b2v,
    const float* __restrict__ W3, const float* __restrict__ b3v,
    const float* __restrict__ W4, const float* __restrict__ b4v,
    float* __restrict__ tab, float* __restrict__ slots, int* __restrict__ cnt)
{
  __shared__ float hA[B_EV][HID];   // 2 KB
  __shared__ float hB[B_EV][HID];   // 2 KB
  const int tid = threadIdx.x;
  const int e   = tid >> 7;        // entry within block, 0..3
  const int k   = tid & 127;       // hidden unit
  const int base = blockIdx.x * B_EV;
  const float dt = T_END_F / (float)(N_TAB - 1);

  // zero the fused kernel's accumulators (runs-before fused via stream order)
  if (blockIdx.x == 0 && tid < 2 * NSLOT + 1){
    if (tid < 2 * NSLOT) slots[tid] = 0.0f;
    else *cnt = 0;
  }

  // layer 1: scalar -> 128  (identical expression to original)
  {
    float x = (float)(base + e) * dt;
    hA[e][k] = tanhf(fmaf(x, W1[k], b1v[k]));
  }
  __syncthreads();

  // layer 2
  hB[e][k] = tanhf(dense_dot(hA[e], W2, k, b2v[k]));
  __syncthreads();

  // layer 3
  hA[e][k] = tanhf(dense_dot(hB[e], W3, k, b3v[k]));
  __syncthreads();

  // layer 4: 128 -> 1, softplus. One wave per entry (even waves), identical
  // expression + xor-tree as original -> bit-identical table values.
  {
    const int wv   = tid >> 6;
    const int lane = tid & 63;
    if ((wv & 1) == 0){
      const int ee = wv >> 1;          // entry handled by this wave
      float wa = W4[lane], wb = W4[lane + 64];
      float b4s = b4v[0];
      float p = hA[ee][lane] * wa + hA[ee][lane + 64] * wb;
      p += __shfl_xor(p, 32);
      p += __shfl_xor(p, 16);
      p += __shfl_xor(p, 8);
      p += __shfl_xor(p, 4);
      p += __shfl_xor(p, 2);
      p += __shfl_xor(p, 1);
      if (lane == 0) tab[base + ee] = softplusf(p + b4s);
    }
  }
}

// ---------- fused: pairs log-sum + MC integral + finalize ----------
// 1536 blocks x 256 threads = 6144 waves. One pair-task per wave (task id =
// gwave, same per-task arithmetic as before). MC thread-per-sample, same idx
// mapping. Block partials -> 16-slot atomics; last block (ticket) finalizes.
__global__ __launch_bounds__(256) void fused_kernel(
    const float* __restrict__ t,        // [16][384]
    const int* __restrict__ seq_lens,   // [16]
    const float* __restrict__ bg,
    const float* __restrict__ tab,
    float* __restrict__ slots,          // [2*NSLOT]: logs then mc
    int* __restrict__ cnt,
    float* __restrict__ out)
{
  __shared__ float sm_tab[N_TAB];       // 16 KB
  __shared__ float redL[4], redM[4];

  const int tid  = threadIdx.x;
  const int lane = tid & 63;
  const int wv   = tid >> 6;
  const float bgv = bg[0];

  // stage table to LDS: 4096 floats / 256 threads = 4 float4 each
  {
    const float4* g4 = (const float4*)tab;
    float4* s4 = (float4*)sm_tab;
#pragma unroll
    for (int q = 0; q < 4; ++q)
      s4[q * 256 + tid] = g4[q * 256 + tid];
  }
  __syncthreads();

  float logsum = 0.0f;   // only lane 0 accumulates
  float mcv    = 0.0f;

  // pairs: one task per wave, task = gwave in [0, 6144)
  {
    unsigned task = (unsigned)(blockIdx.x * 4 + wv);
    unsigned b = task / 384u;
    int i = (int)(task - b * 384u);
    if (i < seq_lens[b]){
      const float* tb = t + b * 384u;
      float ti = tb[i];
      float s = 0.0f;
      for (int j = lane; j < i; j += 64)
        s += TABLE_LDS(ti - tb[j]);
      s += __shfl_xor(s, 32);
      s += __shfl_xor(s, 16);
      s += __shfl_xor(s, 8);
      s += __shfl_xor(s, 4);
      s += __shfl_xor(s, 2);
      s += __shfl_xor(s, 1);
      if (lane == 0) logsum = logf(s + bgv);
    }
  }

  // Monte Carlo sample (same idx mapping as before -> bit-identical samples)
  {
    int idx = blockIdx.x * 256 + tid;
    if (idx < N_MC_TOTAL){
      int l = idx % 384;
      int b = (idx / 384) & 15;
      if (l < seq_lens[b]){
        float tv = t[b * 384 + l];
        float dl = T_END_F - tv;
        float u  = threefry_u01((unsigned)idx);
        mcv = (TABLE_LDS(u * dl) + 1e-10f) * dl;
      }
    }
  }
  mcv += __shfl_xor(mcv, 32);
  mcv += __shfl_xor(mcv, 16);
  mcv += __shfl_xor(mcv, 8);
  mcv += __shfl_xor(mcv, 4);
  mcv += __shfl_xor(mcv, 2);
  mcv += __shfl_xor(mcv, 1);

  if (lane == 0){ redL[wv] = logsum; redM[wv] = mcv; }
  __syncthreads();
  if (tid == 0){
    float bl = redL[0] + redL[1] + redL[2] + redL[3];
    float bm = redM[0] + redM[1] + redM[2] + redM[3];
    int slot = blockIdx.x & (NSLOT - 1);
    atomicAdd(&slots[slot], bl);
    atomicAdd(&slots[NSLOT + slot], bm);
    __threadfence();
    int old = atomicAdd(cnt, 1);
    if (old == (int)gridDim.x - 1){
      // last block: atomic-RMW reads guarantee device-coherent values
      float sl = 0.0f, sm = 0.0f;
      for (int q = 0; q < NSLOT; ++q){
        sl += atomicAdd(&slots[q], 0.0f);
        sm += atomicAdd(&slots[NSLOT + q], 0.0f);
      }
      float lamb_ints_total = sm * (1.0f / 15.0f) + 16.0f * T_END_F * bgv;
      out[0] = -(sl - lamb_ints_total) / 16.0f;
    }
  }
}

extern "C" void kernel_launch(void* const* d_in, const int* in_sizes, int n_in,
                              void* d_out, int out_size, void* d_ws, size_t ws_size,
                              hipStream_t stream)
{
  const float* seq_pads = (const float*)d_in[0];
  const int*   seq_lens = (const int*)d_in[1];
  const float* bg       = (const float*)d_in[2];
  const float* W1 = (const float*)d_in[3];
  const float* b1 = (const float*)d_in[4];
  const float* W2 = (const float*)d_in[5];
  const float* b2 = (const float*)d_in[6];
  const float* W3 = (const float*)d_in[7];
  const float* b3 = (const float*)d_in[8];
  const float* W4 = (const float*)d_in[9];
  const float* b4 = (const float*)d_in[10];
  float* out = (float*)d_out;

  float* tab   = (float*)d_ws;          // N_TAB floats
  float* slots = tab + N_TAB;           // 2*NSLOT floats
  int*   cnt   = (int*)(slots + 2 * NSLOT);

  build_table_kernel<<<NBLK_BUILD, B_THREADS, 0, stream>>>(
      W1, b1, W2, b2, W3, b3, W4, b4, tab, slots, cnt);
  fused_kernel<<<FUSED_BLOCKS, 256, 0, stream>>>(
      seq_pads, seq_lens, bg, tab, slots, cnt, out);
}

// Round 3
// 101.201 us; speedup vs baseline: 1.6049x; 1.3490x over previous
//
#include <hip/hip_runtime.h>
#include <math.h>

#define T_END_F 100.0f
#define N_TAB 4096
#define HID 128
#define N_MC_TOTAL 92160  // 15 * 16 * 384
#define TF_HALF 46080u

// build: 512 blocks x 512 threads; 8 entries/block, 2 entries/thread (ILP=2,
// shared weight loads), 4096 waves = 16 waves/CU.
#define B_EV 8
#define B_THREADS 512
#define NBLK_BUILD (N_TAB / B_EV)   // 512

// fused: 360 blocks x 256 threads = 92160 threads = exactly one MC sample per
// thread; 1440 waves, <=5 pair-tasks per wave. NO atomics / fences: per-block
// partials to distinct addresses, reduced by finalize_kernel.
#define FUSED_BLOCKS 360

// ---------- math helpers ----------
__device__ __forceinline__ float softplusf(float z){
  return fmaxf(z, 0.0f) + log1pf(expf(-fabsf(z)));
}

__device__ __forceinline__ unsigned rotl32(unsigned x, unsigned d){
  return (x << d) | (x >> (32u - d));
}

// Bit-exact JAX threefry2x32 uniform for key(42), total count 92160.
__device__ float threefry_u01(unsigned idx){
  unsigned i0, i1;
  bool second = idx >= TF_HALF;
  if (second){ i0 = idx - TF_HALF; i1 = idx; }
  else       { i0 = idx;           i1 = idx + TF_HALF; }
  const unsigned ks0 = 0u;
  const unsigned ks1 = 42u;
  const unsigned ks2 = 0x1BD11BDAu ^ ks0 ^ ks1;
  unsigned x0 = i0 + ks0;
  unsigned x1 = i1 + ks1;
#define TF_R(r) { x0 += x1; x1 = rotl32(x1, (r)); x1 ^= x0; }
  TF_R(13) TF_R(15) TF_R(26) TF_R(6)
  x0 += ks1; x1 += ks2 + 1u;
  TF_R(17) TF_R(29) TF_R(16) TF_R(24)
  x0 += ks2; x1 += ks0 + 2u;
  TF_R(13) TF_R(15) TF_R(26) TF_R(6)
  x0 += ks0; x1 += ks1 + 3u;
  TF_R(17) TF_R(29) TF_R(16) TF_R(24)
  x0 += ks1; x1 += ks2 + 4u;
  TF_R(13) TF_R(15) TF_R(26) TF_R(6)
  x0 += ks2; x1 += ks0 + 5u;
#undef TF_R
  unsigned bits = second ? x1 : x0;
  unsigned fb = (bits >> 9) | 0x3F800000u;
  return __uint_as_float(fb) - 1.0f;
}

// LDS-resident table lookup
#define TABLE_LDS(xval) ({                                        \
  float _pos = (xval) * ((float)(N_TAB - 1) / T_END_F);           \
  int _i = (int)_pos;                                             \
  if (_i < 0) _i = 0;                                             \
  if (_i > N_TAB - 2) _i = N_TAB - 2;                             \
  float _fr = _pos - (float)_i;                                   \
  float _a = sm_tab[_i];                                          \
  float _b = sm_tab[_i + 1];                                      \
  fmaf(_fr, _b - _a, _a); })

// dense layer for TWO entries sharing weight loads. Per-(entry,unit) fmaf
// chain is the same ascending-j single-accumulator order as all previous
// versions -> bit-identical results.
__device__ __forceinline__ void dense2(
    const float (*__restrict__ hin)[HID], float (*__restrict__ hout)[HID],
    const float* __restrict__ W, const float* __restrict__ bv,
    int k, int e0)
{
  float acc0 = bv[k];
  float acc1 = acc0;
#pragma unroll 4
  for (int j = 0; j < HID; j += 4){
    float w0 = W[(j+0)*HID + k];
    float w1 = W[(j+1)*HID + k];
    float w2 = W[(j+2)*HID + k];
    float w3 = W[(j+3)*HID + k];
    float4 hx = *(const float4*)&hin[e0][j];       // wave-uniform LDS reads
    float4 hy = *(const float4*)&hin[e0 + 4][j];
    acc0 = fmaf(hx.x, w0, acc0);  acc1 = fmaf(hy.x, w0, acc1);
    acc0 = fmaf(hx.y, w1, acc0);  acc1 = fmaf(hy.y, w1, acc1);
    acc0 = fmaf(hx.z, w2, acc0);  acc1 = fmaf(hy.z, w2, acc1);
    acc0 = fmaf(hx.w, w3, acc0);  acc1 = fmaf(hy.w, w3, acc1);
  }
  hout[e0][k]     = tanhf(acc0);
  hout[e0 + 4][k] = tanhf(acc1);
}

// ---------- table build: 512 blocks x 512 threads ----------
__global__ __launch_bounds__(B_THREADS) void build_table_kernel(
    const float* __restrict__ W1, const float* __restrict__ b1v,
    const float* __restrict__ W2, const float* __restrict__ b2v,
    const float* __restrict__ W3, const float* __restrict__ b3v,
    const float* __restrict__ W4, const float* __restrict__ b4v,
    float* __restrict__ tab)
{
  __shared__ float hA[B_EV][HID];   // 4 KB
  __shared__ float hB[B_EV][HID];   // 4 KB
  const int tid = threadIdx.x;
  const int e0  = tid >> 7;        // 0..3 (thread also handles e0+4)
  const int k   = tid & 127;       // hidden unit
  const int base = blockIdx.x * B_EV;
  const float dt = T_END_F / (float)(N_TAB - 1);

  // layer 1: scalar -> 128 (identical per-entry expression)
  {
    float w = W1[k], b = b1v[k];
    float x0 = (float)(base + e0) * dt;
    float x1 = (float)(base + e0 + 4) * dt;
    hA[e0][k]     = tanhf(fmaf(x0, w, b));
    hA[e0 + 4][k] = tanhf(fmaf(x1, w, b));
  }
  __syncthreads();

  dense2(hA, hB, W2, b2v, k, e0);   // layer 2
  __syncthreads();
  dense2(hB, hA, W3, b3v, k, e0);   // layer 3
  __syncthreads();

  // layer 4: 128 -> 1, softplus. Wave wv owns entry wv; identical expression
  // + xor-tree as all previous versions -> bit-identical table values.
  {
    const int wv   = tid >> 6;       // 0..7
    const int lane = tid & 63;
    float wa = W4[lane], wb = W4[lane + 64];
    float b4s = b4v[0];
    float p = hA[wv][lane] * wa + hA[wv][lane + 64] * wb;
    p += __shfl_xor(p, 32);
    p += __shfl_xor(p, 16);
    p += __shfl_xor(p, 8);
    p += __shfl_xor(p, 4);
    p += __shfl_xor(p, 2);
    p += __shfl_xor(p, 1);
    if (lane == 0) tab[base + wv] = softplusf(p + b4s);
  }
}

// ---------- fused: pairs log-sum + MC integral ----------
// 360 blocks x 256 threads. Pair-tasks: task = gwave + kk*1440 (<6144), same
// per-task arithmetic as before. MC: idx = blockIdx*256+tid, exactly covers
// 92160 samples with the same idx mapping -> bit-identical samples.
// Per-block partials go to plain global stores (no atomics, no fences).
__global__ __launch_bounds__(256) void fused_kernel(
    const float* __restrict__ t,        // [16][384]
    const int* __restrict__ seq_lens,   // [16]
    const float* __restrict__ bg,
    const float* __restrict__ tab,
    float* __restrict__ partials)       // [2*FUSED_BLOCKS]: logs then mc
{
  __shared__ float sm_tab[N_TAB];       // 16 KB
  __shared__ float redL[4], redM[4];

  const int tid  = threadIdx.x;
  const int lane = tid & 63;
  const int wv   = tid >> 6;
  const float bgv = bg[0];

  // stage table to LDS: 4096 floats / 256 threads = 4 float4 each
  {
    const float4* g4 = (const float4*)tab;
    float4* s4 = (float4*)sm_tab;
#pragma unroll
    for (int q = 0; q < 4; ++q)
      s4[q * 256 + tid] = g4[q * 256 + tid];
  }
  __syncthreads();

  float logsum = 0.0f;   // only lane 0 accumulates
  float mcv    = 0.0f;

  // pairs: tasks gwave + kk*1440, kk = 0..4
  const int gwave = blockIdx.x * 4 + wv;   // 0..1439
#pragma unroll
  for (int kk = 0; kk < 5; ++kk){
    unsigned task = (unsigned)gwave + (unsigned)kk * 1440u;
    if (task < 6144u){
      unsigned b = task / 384u;
      int i = (int)(task - b * 384u);
      if (i < seq_lens[b]){
        const float* tb = t + b * 384u;
        float ti = tb[i];
        float s = 0.0f;
        for (int j = lane; j < i; j += 64)
          s += TABLE_LDS(ti - tb[j]);
        s += __shfl_xor(s, 32);
        s += __shfl_xor(s, 16);
        s += __shfl_xor(s, 8);
        s += __shfl_xor(s, 4);
        s += __shfl_xor(s, 2);
        s += __shfl_xor(s, 1);
        if (lane == 0) logsum += logf(s + bgv);
      }
    }
  }

  // Monte Carlo sample (idx always < 92160 here)
  {
    int idx = blockIdx.x * 256 + tid;
    int l = idx % 384;
    int b = (idx / 384) & 15;
    if (l < seq_lens[b]){
      float tv = t[b * 384 + l];
      float dl = T_END_F - tv;
      float u  = threefry_u01((unsigned)idx);
      mcv = (TABLE_LDS(u * dl) + 1e-10f) * dl;
    }
  }
  mcv += __shfl_xor(mcv, 32);
  mcv += __shfl_xor(mcv, 16);
  mcv += __shfl_xor(mcv, 8);
  mcv += __shfl_xor(mcv, 4);
  mcv += __shfl_xor(mcv, 2);
  mcv += __shfl_xor(mcv, 1);

  if (lane == 0){ redL[wv] = logsum; redM[wv] = mcv; }
  __syncthreads();
  if (tid == 0){
    partials[blockIdx.x]                = redL[0] + redL[1] + redL[2] + redL[3];
    partials[FUSED_BLOCKS + blockIdx.x] = redM[0] + redM[1] + redM[2] + redM[3];
  }
}

// ---------- finalize: deterministic 16-residue reduction, 1 wave ----------
__global__ __launch_bounds__(64) void finalize_kernel(
    const float* __restrict__ partials,
    const float* __restrict__ bg,
    float* __restrict__ out)
{
  __shared__ float sl16[16], sm16[16];
  const int lane = threadIdx.x;
  if (lane < 16){
    float a = 0.0f, b = 0.0f;
    for (int p = lane; p < FUSED_BLOCKS; p += 16){
      a += partials[p];
      b += partials[FUSED_BLOCKS + p];
    }
    sl16[lane] = a;
    sm16[lane] = b;
  }
  __syncthreads();
  if (lane == 0){
    float sl = 0.0f, sm = 0.0f;
#pragma unroll
    for (int q = 0; q < 16; ++q){ sl += sl16[q]; sm += sm16[q]; }
    float bgv = bg[0];
    float lamb_ints_total = sm * (1.0f / 15.0f) + 16.0f * T_END_F * bgv;
    out[0] = -(sl - lamb_ints_total) / 16.0f;
  }
}

extern "C" void kernel_launch(void* const* d_in, const int* in_sizes, int n_in,
                              void* d_out, int out_size, void* d_ws, size_t ws_size,
                              hipStream_t stream)
{
  const float* seq_pads = (const float*)d_in[0];
  const int*   seq_lens = (const int*)d_in[1];
  const float* bg       = (const float*)d_in[2];
  const float* W1 = (const float*)d_in[3];
  const float* b1 = (const float*)d_in[4];
  const float* W2 = (const float*)d_in[5];
  const float* b2 = (const float*)d_in[6];
  const float* W3 = (const float*)d_in[7];
  const float* b3 = (const float*)d_in[8];
  const float* W4 = (const float*)d_in[9];
  const float* b4 = (const float*)d_in[10];
  float* out = (float*)d_out;

  float* tab      = (float*)d_ws;          // N_TAB floats
  float* partials = tab + N_TAB;           // 2*FUSED_BLOCKS floats

  build_table_kernel<<<NBLK_BUILD, B_THREADS, 0, stream>>>(
      W1, b1, W2, b2, W3, b3, W4, b4, tab);
  fused_kernel<<<FUSED_BLOCKS, 256, 0, stream>>>(
      seq_pads, seq_lens, bg, tab, partials);
  finalize_kernel<<<1, 64, 0, stream>>>(partials, bg, out);
}

// Round 4
// 96.969 us; speedup vs baseline: 1.6749x; 1.0436x over previous
//
#include <hip/hip_runtime.h>
#include <math.h>

#define T_END_F 100.0f
#define N_TAB 4096
#define HID 128
#define N_MC_TOTAL 92160  // 15 * 16 * 384
#define TF_HALF 46080u

// build: 512 blocks x 256 threads; 8 entries/block, 4 entries/thread
// (weight reuse 4, ILP 4). 2048 waves = 8 waves/CU.
#define B_EV 8
#define B_THREADS 256
#define NBLK_BUILD (N_TAB / B_EV)   // 512

// fused: 360 blocks x 512 threads = 2880 waves = 11 waves/CU.
// MC: idx = blockIdx*512+tid covers [0,92160) exactly (blocks 0..179).
// Pairs: <=3 tasks per wave. Plain per-block partial stores, no atomics.
#define FUSED_BLOCKS 360
#define F_THREADS 512

// ---------- math helpers ----------
__device__ __forceinline__ float softplusf(float z){
  return fmaxf(z, 0.0f) + log1pf(expf(-fabsf(z)));
}

__device__ __forceinline__ unsigned rotl32(unsigned x, unsigned d){
  return (x << d) | (x >> (32u - d));
}

// Bit-exact JAX threefry2x32 uniform for key(42), total count 92160.
__device__ float threefry_u01(unsigned idx){
  unsigned i0, i1;
  bool second = idx >= TF_HALF;
  if (second){ i0 = idx - TF_HALF; i1 = idx; }
  else       { i0 = idx;           i1 = idx + TF_HALF; }
  const unsigned ks0 = 0u;
  const unsigned ks1 = 42u;
  const unsigned ks2 = 0x1BD11BDAu ^ ks0 ^ ks1;
  unsigned x0 = i0 + ks0;
  unsigned x1 = i1 + ks1;
#define TF_R(r) { x0 += x1; x1 = rotl32(x1, (r)); x1 ^= x0; }
  TF_R(13) TF_R(15) TF_R(26) TF_R(6)
  x0 += ks1; x1 += ks2 + 1u;
  TF_R(17) TF_R(29) TF_R(16) TF_R(24)
  x0 += ks2; x1 += ks0 + 2u;
  TF_R(13) TF_R(15) TF_R(26) TF_R(6)
  x0 += ks0; x1 += ks1 + 3u;
  TF_R(17) TF_R(29) TF_R(16) TF_R(24)
  x0 += ks1; x1 += ks2 + 4u;
  TF_R(13) TF_R(15) TF_R(26) TF_R(6)
  x0 += ks2; x1 += ks0 + 5u;
#undef TF_R
  unsigned bits = second ? x1 : x0;
  unsigned fb = (bits >> 9) | 0x3F800000u;
  return __uint_as_float(fb) - 1.0f;
}

// LDS-resident table lookup
#define TABLE_LDS(xval) ({                                        \
  float _pos = (xval) * ((float)(N_TAB - 1) / T_END_F);           \
  int _i = (int)_pos;                                             \
  if (_i < 0) _i = 0;                                             \
  if (_i > N_TAB - 2) _i = N_TAB - 2;                             \
  float _fr = _pos - (float)_i;                                   \
  float _a = sm_tab[_i];                                          \
  float _b = sm_tab[_i + 1];                                      \
  fmaf(_fr, _b - _a, _a); })

// dense layer for FOUR entries sharing every weight load (reuse 4, ILP 4).
// Per-(entry,unit) fmaf chain is the same ascending-j single-accumulator
// order as all previous versions -> bit-identical results.
__device__ __forceinline__ void dense4(
    const float (*__restrict__ hin)[HID], float (*__restrict__ hout)[HID],
    const float* __restrict__ W, const float* __restrict__ bv,
    int k, int e0)
{
  float acc0 = bv[k];
  float acc1 = acc0, acc2 = acc0, acc3 = acc0;
#pragma unroll 4
  for (int j = 0; j < HID; j += 4){
    float w0 = W[(j+0)*HID + k];
    float w1 = W[(j+1)*HID + k];
    float w2 = W[(j+2)*HID + k];
    float w3 = W[(j+3)*HID + k];
    float4 h0 = *(const float4*)&hin[e0 + 0][j];   // wave-uniform LDS broadcast
    float4 h1 = *(const float4*)&hin[e0 + 1][j];
    float4 h2 = *(const float4*)&hin[e0 + 2][j];
    float4 h3 = *(const float4*)&hin[e0 + 3][j];
    acc0 = fmaf(h0.x, w0, acc0);  acc1 = fmaf(h1.x, w0, acc1);
    acc2 = fmaf(h2.x, w0, acc2);  acc3 = fmaf(h3.x, w0, acc3);
    acc0 = fmaf(h0.y, w1, acc0);  acc1 = fmaf(h1.y, w1, acc1);
    acc2 = fmaf(h2.y, w1, acc2);  acc3 = fmaf(h3.y, w1, acc3);
    acc0 = fmaf(h0.z, w2, acc0);  acc1 = fmaf(h1.z, w2, acc1);
    acc2 = fmaf(h2.z, w2, acc2);  acc3 = fmaf(h3.z, w2, acc3);
    acc0 = fmaf(h0.w, w3, acc0);  acc1 = fmaf(h1.w, w3, acc1);
    acc2 = fmaf(h2.w, w3, acc2);  acc3 = fmaf(h3.w, w3, acc3);
  }
  hout[e0 + 0][k] = tanhf(acc0);
  hout[e0 + 1][k] = tanhf(acc1);
  hout[e0 + 2][k] = tanhf(acc2);
  hout[e0 + 3][k] = tanhf(acc3);
}

// ---------- table build: 512 blocks x 256 threads ----------
__global__ __launch_bounds__(B_THREADS) void build_table_kernel(
    const float* __restrict__ W1, const float* __restrict__ b1v,
    const float* __restrict__ W2, const float* __restrict__ b2v,
    const float* __restrict__ W3, const float* __restrict__ b3v,
    const float* __restrict__ W4, const float* __restrict__ b4v,
    float* __restrict__ tab)
{
  __shared__ float hA[B_EV][HID];   // 4 KB
  __shared__ float hB[B_EV][HID];   // 4 KB
  const int tid = threadIdx.x;
  const int k   = tid & 127;       // hidden unit
  const int g   = tid >> 7;        // 0/1: which 4-entry group
  const int e0  = g * 4;
  const int base = blockIdx.x * B_EV;
  const float dt = T_END_F / (float)(N_TAB - 1);

  // layer 1: scalar -> 128 (identical per-entry expression)
  {
    float w = W1[k], b = b1v[k];
#pragma unroll
    for (int q = 0; q < 4; ++q){
      float x = (float)(base + e0 + q) * dt;
      hA[e0 + q][k] = tanhf(fmaf(x, w, b));
    }
  }
  __syncthreads();

  dense4(hA, hB, W2, b2v, k, e0);   // layer 2
  __syncthreads();
  dense4(hB, hA, W3, b3v, k, e0);   // layer 3
  __syncthreads();

  // layer 4: 128 -> 1, softplus. Wave wv owns entries wv*2, wv*2+1;
  // identical expression + xor-tree -> bit-identical table values.
  {
    const int wv   = tid >> 6;       // 0..3
    const int lane = tid & 63;
    float wa = W4[lane], wb = W4[lane + 64];
    float b4s = b4v[0];
#pragma unroll
    for (int r = 0; r < 2; ++r){
      int e = wv * 2 + r;
      float p = hA[e][lane] * wa + hA[e][lane + 64] * wb;
      p += __shfl_xor(p, 32);
      p += __shfl_xor(p, 16);
      p += __shfl_xor(p, 8);
      p += __shfl_xor(p, 4);
      p += __shfl_xor(p, 2);
      p += __shfl_xor(p, 1);
      if (lane == 0) tab[base + e] = softplusf(p + b4s);
    }
  }
}

// ---------- fused: pairs log-sum + MC integral ----------
__global__ __launch_bounds__(F_THREADS) void fused_kernel(
    const float* __restrict__ t,        // [16][384]
    const int* __restrict__ seq_lens,   // [16]
    const float* __restrict__ bg,
    const float* __restrict__ tab,
    float* __restrict__ partials)       // [2*FUSED_BLOCKS]: logs then mc
{
  __shared__ float sm_tab[N_TAB];       // 16 KB
  __shared__ float redL[8], redM[8];

  const int tid  = threadIdx.x;
  const int lane = tid & 63;
  const int wv   = tid >> 6;           // 0..7
  const float bgv = bg[0];

  // stage table to LDS: 4096 floats / 512 threads = 2 float4 each
  {
    const float4* g4 = (const float4*)tab;
    float4* s4 = (float4*)sm_tab;
#pragma unroll
    for (int q = 0; q < 2; ++q)
      s4[q * F_THREADS + tid] = g4[q * F_THREADS + tid];
  }
  __syncthreads();

  float logsum = 0.0f;   // only lane 0 accumulates
  float mcv    = 0.0f;

  // pairs: tasks gwave + kk*2880, kk = 0..2 (task < 6144)
  const int gwave = blockIdx.x * 8 + wv;   // 0..2879
#pragma unroll
  for (int kk = 0; kk < 3; ++kk){
    unsigned task = (unsigned)gwave + (unsigned)kk * 2880u;
    if (task < 6144u){
      unsigned b = task / 384u;
      int i = (int)(task - b * 384u);
      if (i < seq_lens[b]){
        const float* tb = t + b * 384u;
        float ti = tb[i];
        float s = 0.0f;
        for (int j = lane; j < i; j += 64)
          s += TABLE_LDS(ti - tb[j]);
        s += __shfl_xor(s, 32);
        s += __shfl_xor(s, 16);
        s += __shfl_xor(s, 8);
        s += __shfl_xor(s, 4);
        s += __shfl_xor(s, 2);
        s += __shfl_xor(s, 1);
        if (lane == 0) logsum += logf(s + bgv);
      }
    }
  }

  // Monte Carlo sample: value is a function of idx only -> bit-identical
  {
    int idx = blockIdx.x * F_THREADS + tid;
    if (idx < N_MC_TOTAL){
      int l = idx % 384;
      int b = (idx / 384) & 15;
      if (l < seq_lens[b]){
        float tv = t[b * 384 + l];
        float dl = T_END_F - tv;
        float u  = threefry_u01((unsigned)idx);
        mcv = (TABLE_LDS(u * dl) + 1e-10f) * dl;
      }
    }
  }
  mcv += __shfl_xor(mcv, 32);
  mcv += __shfl_xor(mcv, 16);
  mcv += __shfl_xor(mcv, 8);
  mcv += __shfl_xor(mcv, 4);
  mcv += __shfl_xor(mcv, 2);
  mcv += __shfl_xor(mcv, 1);

  if (lane == 0){ redL[wv] = logsum; redM[wv] = mcv; }
  __syncthreads();
  if (tid == 0){
    float bl = 0.0f, bm = 0.0f;
#pragma unroll
    for (int q = 0; q < 8; ++q){ bl += redL[q]; bm += redM[q]; }
    partials[blockIdx.x]                = bl;
    partials[FUSED_BLOCKS + blockIdx.x] = bm;
  }
}

// ---------- finalize: deterministic 16-residue reduction, 1 wave ----------
__global__ __launch_bounds__(64) void finalize_kernel(
    const float* __restrict__ partials,
    const float* __restrict__ bg,
    float* __restrict__ out)
{
  __shared__ float sl16[16], sm16[16];
  const int lane = threadIdx.x;
  if (lane < 16){
    float a = 0.0f, b = 0.0f;
    for (int p = lane; p < FUSED_BLOCKS; p += 16){
      a += partials[p];
      b += partials[FUSED_BLOCKS + p];
    }
    sl16[lane] = a;
    sm16[lane] = b;
  }
  __syncthreads();
  if (lane == 0){
    float sl = 0.0f, sm = 0.0f;
#pragma unroll
    for (int q = 0; q < 16; ++q){ sl += sl16[q]; sm += sm16[q]; }
    float bgv = bg[0];
    float lamb_ints_total = sm * (1.0f / 15.0f) + 16.0f * T_END_F * bgv;
    out[0] = -(sl - lamb_ints_total) / 16.0f;
  }
}

extern "C" void kernel_launch(void* const* d_in, const int* in_sizes, int n_in,
                              void* d_out, int out_size, void* d_ws, size_t ws_size,
                              hipStream_t stream)
{
  const float* seq_pads = (const float*)d_in[0];
  const int*   seq_lens = (const int*)d_in[1];
  const float* bg       = (const float*)d_in[2];
  const float* W1 = (const float*)d_in[3];
  const float* b1 = (const float*)d_in[4];
  const float* W2 = (const float*)d_in[5];
  const float* b2 = (const float*)d_in[6];
  const float* W3 = (const float*)d_in[7];
  const float* b3 = (const float*)d_in[8];
  const float* W4 = (const float*)d_in[9];
  const float* b4 = (const float*)d_in[10];
  float* out = (float*)d_out;

  float* tab      = (float*)d_ws;          // N_TAB floats
  float* partials = tab + N_TAB;           // 2*FUSED_BLOCKS floats

  build_table_kernel<<<NBLK_BUILD, B_THREADS, 0, stream>>>(
      W1, b1, W2, b2, W3, b3, W4, b4, tab);
  fused_kernel<<<FUSED_BLOCKS, F_THREADS, 0, stream>>>(
      seq_pads, seq_lens, bg, tab, partials);
  finalize_kernel<<<1, 64, 0, stream>>>(partials, bg, out);
}